// Round 2
// baseline (1275.898 us; speedup 1.0000x reference)
//
#include <hip/hip_runtime.h>
#include <cstdint>
#include <cstddef>

// MultiScaleQuantizer: z (256,32,16,16) fp32, embed (4096,32) fp32.
// Outputs concat (fp32): f_hat (2097152), idx@pn=1..16 (87296 total), loss (1).

#define B_   256
#define C_   32
#define V_   4096
#define NTOT 2097152   // 256*32*16*16

// ---------------- prep: ||e||^2 per code ----------------
__global__ __launch_bounds__(256) void prep_se_kernel(
    const float* __restrict__ embed, float* __restrict__ se)
{
  int v = blockIdx.x * 256 + threadIdx.x;
  if (v >= V_) return;
  float s = 0.f;
#pragma unroll
  for (int c = 0; c < 32; ++c) {
    float e = embed[(size_t)v * 32 + c];
    s += e * e;                       // sequential, matches ref sum order
  }
  se[v] = s;
}

// ---------------- init: f_rest = z, f_hat(out) = 0 ----------------
__global__ __launch_bounds__(256) void init_kernel(
    const float* __restrict__ z, float* __restrict__ f_rest,
    float* __restrict__ f_hat)
{
  int t = blockIdx.x * 256 + threadIdx.x;
  f_rest[t] = z[t];
  f_hat[t] = 0.f;
}

// ---------------- bicubic weight tables + zero loss accumulators ----------
// tbl layout: [pn_i in {1,2,4,8}][16 output rows][8 cols max]
__global__ void tables_kernel(float* __restrict__ tbl, float* __restrict__ losses)
{
  int tid = threadIdx.x;
  if (tid < 8) losses[tid] = 0.f;
  if (tid >= 64) return;
  int pn_i = tid >> 4;          // 0..3 -> pn = 1,2,4,8
  int o    = tid & 15;          // output row
  int pn   = 1 << pn_i;
  double scale = (double)pn / 16.0;
  double x  = (o + 0.5) * scale - 0.5;
  double x0 = floor(x);
  double tf = x - x0;
  float row[8];
#pragma unroll
  for (int h = 0; h < 8; ++h) row[h] = 0.f;
  const double A = -0.75;
#pragma unroll
  for (int off = -1; off <= 2; ++off) {
    double s = fabs(tf - (double)off);
    double cub;
    if (s <= 1.0)      cub = ((A + 2.0) * s - (A + 3.0)) * s * s + 1.0;
    else if (s < 2.0)  cub = (((s - 5.0) * s + 8.0) * s - 4.0) * A;
    else               cub = 0.0;
    int idx = (int)x0 + off;
    idx = min(max(idx, 0), pn - 1);
    row[idx] = (float)((double)row[idx] + cub);
  }
#pragma unroll
  for (int h = 0; h < 8; ++h) tbl[pn_i * 128 + o * 8 + h] = row[h];
}

// ---------------- area downsample + pack to (N,32) ----------------
__global__ __launch_bounds__(256) void down_pack_kernel(
    const float* __restrict__ f_rest, float* __restrict__ zpack, int pn)
{
  int t = blockIdx.x * 256 + threadIdx.x;
  int c = t & 31;
  int n = t >> 5;
  int pn2 = pn * pn;
  int pw = n % pn;
  int ph = (n / pn) % pn;
  int b  = n / pn2;
  int k  = 16 / pn;
  const float* src = f_rest + (size_t)(b * 32 + c) * 256;
  float s = 0.f;
  for (int i = 0; i < k; ++i)
    for (int j = 0; j < k; ++j)
      s += src[(ph * k + i) * 16 + (pw * k + j)];
  zpack[(size_t)n * 32 + c] = s * (1.0f / (k * k));   // 1/k^2 pow2: exact
}

// ---------------- fused distance + argmin (register/scalar-broadcast) -------
// 1 thread = 1 point; z row in VGPRs; code index v is block-uniform so the
// embed row + se[v] loads are scalar (s_load) -> zero LDS, VALU-only inner.
__global__ void vq_point_kernel(
    const float* __restrict__ zpack, const float* __restrict__ se,
    const float* __restrict__ embed, float2* __restrict__ partials,
    int vchunk, int nvch)
{
  const int n  = blockIdx.x * blockDim.x + threadIdx.x;
  const int v0 = blockIdx.y * vchunk;

  const float4* zr4 = (const float4*)(zpack + (size_t)n * 32);
  float z[32];
#pragma unroll
  for (int i = 0; i < 8; ++i) {
    float4 t = zr4[i];
    z[4 * i + 0] = t.x; z[4 * i + 1] = t.y;
    z[4 * i + 2] = t.z; z[4 * i + 3] = t.w;
  }
  float sz = 0.f;
#pragma unroll
  for (int c = 0; c < 32; ++c) sz = fmaf(z[c], z[c], sz);

  float mind = 3.4e38f;
  int   mini = 0x7fffffff;
#pragma unroll 4
  for (int cc = 0; cc < vchunk; ++cc) {
    int v = v0 + cc;                              // block-uniform
    const float4* er = (const float4*)(embed + (size_t)v * 32);
    float dot = 0.f;
#pragma unroll
    for (int i = 0; i < 8; ++i) {
      float4 e = er[i];
      dot = fmaf(z[4 * i + 0], e.x, dot);
      dot = fmaf(z[4 * i + 1], e.y, dot);
      dot = fmaf(z[4 * i + 2], e.z, dot);
      dot = fmaf(z[4 * i + 3], e.w, dot);
    }
    // matches ref: (sz - 2*dot) + se   (strict <: first index wins)
    float d = fmaf(-2.0f, dot, sz) + se[v];
    if (d < mind) { mind = d; mini = v; }
  }
  partials[(size_t)n * nvch + blockIdx.y] = make_float2(mind, __int_as_float(mini));
}

// ------------- reduce partial argmins over chunks + fused loss -------------
__global__ __launch_bounds__(256) void vq_reduce_loss_kernel(
    const float2* __restrict__ partials, const float* __restrict__ zpack,
    const float* __restrict__ embed, int nvch,
    int* __restrict__ idx_list, float* __restrict__ idx_out_f,
    float* __restrict__ loss_slot)
{
  int n = blockIdx.x * 256 + threadIdx.x;
  float bd = 3.4e38f; int bi = 0x7fffffff;
  for (int t = 0; t < nvch; ++t) {
    float2 r = partials[(size_t)n * nvch + t];
    int v = __float_as_int(r.y);
    if (r.x < bd || (r.x == bd && v < bi)) { bd = r.x; bi = v; }
  }
  idx_list[n] = bi;
  idx_out_f[n] = (float)bi;          // harness reads idx as fp32

  // loss contribution: sum (embed[idx]-z)^2 (tolerance is loose; order free)
  const float* zp = zpack + (size_t)n * 32;
  const float* ep = embed + (size_t)bi * 32;
  float s = 0.f;
#pragma unroll
  for (int c = 0; c < 32; ++c) {
    float d = ep[c] - zp[c];
    s = fmaf(d, d, s);
  }
#pragma unroll
  for (int off = 32; off > 0; off >>= 1) s += __shfl_down(s, off, 64);
  if ((threadIdx.x & 63) == 0) atomicAdd(loss_slot, s);
}

// ---------------- bicubic upsample + f_hat += / f_rest -= ----------------
// t = ((b*32+c)*16+o)*16+p
__global__ __launch_bounds__(256) void up_update_kernel(
    const float* __restrict__ embed, const int* __restrict__ idx_list,
    const float* __restrict__ tbl, float* __restrict__ f_hat,
    float* __restrict__ f_rest, int pn)
{
  int t = blockIdx.x * 256 + threadIdx.x;
  int p = t & 15;
  int o = (t >> 4) & 15;
  int c = (t >> 8) & 31;
  int b = t >> 13;
  const float* Wo = tbl + o * 8;
  const float* Wp = tbl + p * 8;
  float acc = 0.f;
  for (int w = 0; w < pn; ++w) {
    float inner = 0.f;                 // reference: h-einsum first, then w
    for (int h = 0; h < pn; ++h) {
      int idx = idx_list[(b * pn + h) * pn + w];
      inner = fmaf(Wo[h], embed[(size_t)idx * 32 + c], inner);
    }
    acc = fmaf(Wp[w], inner, acc);
  }
  f_hat[t] += acc;
  f_rest[t] -= acc;
}

// ---------------- last scale (pn=16): f_hat += embed[idx] ----------------
__global__ __launch_bounds__(256) void final_add_kernel(
    const float* __restrict__ embed, const int* __restrict__ idx_list,
    float* __restrict__ f_hat)
{
  int t = blockIdx.x * 256 + threadIdx.x;
  int s = t & 255;
  int c = (t >> 8) & 31;
  int b = t >> 13;
  int n = b * 256 + s;
  f_hat[t] += embed[(size_t)idx_list[n] * 32 + c];
}

// ---------------- combine loss ----------------
__global__ void loss_final_kernel(const float* __restrict__ losses,
                                  float* __restrict__ out_loss)
{
  if (threadIdx.x != 0) return;
  const float numel[5] = {8192.f, 32768.f, 131072.f, 524288.f, 2097152.f};
  float v = 0.f;
  for (int i = 0; i < 5; ++i) {
    float m = losses[i] / numel[i];
    float li = 0.25f * m + m;          // beta*mean + mean
    v = v + li;
  }
  out_loss[0] = v / 5.f;
}

// =========================== host launcher ===========================
extern "C" void kernel_launch(void* const* d_in, const int* in_sizes, int n_in,
                              void* d_out, int out_size, void* d_ws, size_t ws_size,
                              hipStream_t stream)
{
  const float* z     = (const float*)d_in[0];
  const float* embed = (const float*)d_in[1];
  float* out = (float*)d_out;
  float* ws  = (float*)d_ws;

  // ws layout (floats); peak 4526600 floats (~18.1 MB), below r1's proven use
  float*  f_rest   = ws;                       // 2097152
  float*  zpack    = ws + 2097152;             // 2097152
  float*  se       = ws + 4194304;             // 4096
  float2* partials = (float2*)(ws + 4198400);  // up to 131072 float2
  int*    idx_list = (int*)(ws + 4460544);     // 65536 ints
  float*  losses   = ws + 4526080;             // 8
  float*  tables   = ws + 4526088;             // 512

  prep_se_kernel<<<V_ / 256, 256, 0, stream>>>(embed, se);
  init_kernel<<<NTOT / 256, 256, 0, stream>>>(z, f_rest, out);
  tables_kernel<<<1, 64, 0, stream>>>(tables, losses);

  const int PN[5]  = {1, 2, 4, 8, 16};
  const int BLK[5] = {64, 64, 64, 256, 256};
  const int NV[5]  = {32, 16, 16, 8, 2};    // codebook chunks per scale
  int idx_off = NTOT;
  for (int i = 0; i < 5; ++i) {
    int pn = PN[i];
    int N  = B_ * pn * pn;
    int nvch = NV[i];
    int vchunk = V_ / nvch;
    down_pack_kernel<<<(N * 32) / 256, 256, 0, stream>>>(f_rest, zpack, pn);
    dim3 gA(N / BLK[i], nvch);
    vq_point_kernel<<<gA, BLK[i], 0, stream>>>(zpack, se, embed, partials,
                                               vchunk, nvch);
    vq_reduce_loss_kernel<<<N / 256, 256, 0, stream>>>(
        partials, zpack, embed, nvch, idx_list, out + idx_off, losses + i);
    if (i < 4)
      up_update_kernel<<<NTOT / 256, 256, 0, stream>>>(embed, idx_list,
                                                       tables + i * 128, out,
                                                       f_rest, pn);
    else
      final_add_kernel<<<NTOT / 256, 256, 0, stream>>>(embed, idx_list, out);
    idx_off += N;
  }
  loss_final_kernel<<<1, 1, 0, stream>>>(losses, out + 2184448);
}

// Round 3
// 670.855 us; speedup vs baseline: 1.9019x; 1.9019x over previous
//
#include <hip/hip_runtime.h>
#include <cstdint>
#include <cstddef>

// MultiScaleQuantizer: z (256,32,16,16) fp32, embed (4096,32) fp32.
// Outputs concat (fp32): f_hat (2097152), idx@pn=1..16 (87296), loss (1).

#define B_   256
#define V_   4096
#define NTOT 2097152   // 256*32*16*16

typedef float v2f __attribute__((ext_vector_type(2)));

// ---------------- setup: f_rest=z, f_hat=0, zpack@pn1, se, tables, keys ----
__global__ __launch_bounds__(256) void setup_kernel(
    const float* __restrict__ z, const float* __restrict__ embed,
    float* __restrict__ f_rest, float* __restrict__ f_hat,
    float* __restrict__ zpack, float* __restrict__ se,
    float* __restrict__ tables, float* __restrict__ losses,
    unsigned long long* __restrict__ keys)
{
  const int tid = threadIdx.x;
  const int t = blockIdx.x * 256 + tid;
  float v = z[t];
  f_rest[t] = v;
  f_hat[t] = 0.f;

  // zpack for pn=1: block = one (b,c) plane; n=b -> zpack[b*32+c]=blockIdx.x
  __shared__ float sm[256];
  sm[tid] = v;
  __syncthreads();
  if (tid == 0) {
    float s = 0.f;
    for (int i = 0; i < 256; ++i) s += sm[i];   // ref's i,j order (linear)
    zpack[blockIdx.x] = s * (1.0f / 256.0f);
  }

  if (blockIdx.x < 16) {                        // se: 16*256 = 4096 codes
    int code = blockIdx.x * 256 + tid;
    float s = 0.f;
#pragma unroll
    for (int c = 0; c < 32; ++c) {
      float e = embed[(size_t)code * 32 + c];
      s += e * e;                                // sequential like ref
    }
    se[code] = s;
  } else if (blockIdx.x == 16) {
    if (tid >= 64 && tid < 72) losses[tid - 64] = 0.f;
    if (tid < 64) {
      int pn_i = tid >> 4;          // 0..3 -> pn = 1,2,4,8
      int o    = tid & 15;
      int pn   = 1 << pn_i;
      double scale = (double)pn / 16.0;
      double x  = (o + 0.5) * scale - 0.5;
      double x0 = floor(x);
      double tf = x - x0;
      float row[8];
#pragma unroll
      for (int h = 0; h < 8; ++h) row[h] = 0.f;
      const double A = -0.75;
#pragma unroll
      for (int off = -1; off <= 2; ++off) {
        double s = fabs(tf - (double)off);
        double cub;
        if (s <= 1.0)      cub = ((A + 2.0) * s - (A + 3.0)) * s * s + 1.0;
        else if (s < 2.0)  cub = (((s - 5.0) * s + 8.0) * s - 4.0) * A;
        else               cub = 0.0;
        int idx = (int)x0 + off;
        idx = min(max(idx, 0), pn - 1);
        row[idx] = (float)((double)row[idx] + cub);  // numpy f32 += f64
      }
#pragma unroll
      for (int h = 0; h < 8; ++h) tables[pn_i * 128 + o * 8 + h] = row[h];
    }
  } else if (blockIdx.x == 17) {
    keys[tid] = ~0ull;                           // keys for pn=1 (N=256)
  }
}

// ---------------- fused distance + argmin, u64 atomicMin combine ----------
// 1 thread = 1 point; z row in VGPRs; code index block-uniform -> embed/se
// loads scalarize (s_load). 2 codes in flight x 2 pk-chains each.
__global__ __launch_bounds__(256) void vq_point_kernel(
    const float* __restrict__ zpack, const float* __restrict__ se,
    const float* __restrict__ embed, unsigned long long* __restrict__ keys,
    int vchunk)
{
  const int n  = blockIdx.x * blockDim.x + threadIdx.x;
  const int v0 = blockIdx.y * vchunk;

  const float4* zr4 = (const float4*)(zpack + (size_t)n * 32);
  v2f z[16];
#pragma unroll
  for (int i = 0; i < 8; ++i) {
    float4 t = zr4[i];
    z[2 * i]     = v2f{t.x, t.y};
    z[2 * i + 1] = v2f{t.z, t.w};
  }
  // sz: constant offset per point -> cannot affect this point's argmin
  v2f szv = {0.f, 0.f};
#pragma unroll
  for (int i = 0; i < 16; ++i) szv = __builtin_elementwise_fma(z[i], z[i], szv);
  const float sz = szv.x + szv.y;

  float mind = 3.4e38f;
  int   mini = 0x7fffffff;
  const v2f*   eb  = (const v2f*)(embed + (size_t)v0 * 32);
  const float* seb = se + v0;
  for (int cc = 0; cc < vchunk; cc += 2) {
    const v2f* eA = eb + (size_t)cc * 16;
    const v2f* eB = eA + 16;
    v2f a0 = {0.f, 0.f}, a1 = {0.f, 0.f};
    v2f b0 = {0.f, 0.f}, b1 = {0.f, 0.f};
#pragma unroll
    for (int i = 0; i < 8; ++i) {
      a0 = __builtin_elementwise_fma(z[2 * i],     eA[2 * i],     a0);
      a1 = __builtin_elementwise_fma(z[2 * i + 1], eA[2 * i + 1], a1);
      b0 = __builtin_elementwise_fma(z[2 * i],     eB[2 * i],     b0);
      b1 = __builtin_elementwise_fma(z[2 * i + 1], eB[2 * i + 1], b1);
    }
    float dotA = (a0.x + a0.y) + (a1.x + a1.y);
    float dotB = (b0.x + b0.y) + (b1.x + b1.y);
    // 2*dot is exact (exponent bump) -> fmaf(-2,dot,sz) == ref's (sz-2dot)
    float dA = fmaf(-2.0f, dotA, sz) + seb[cc];
    float dB = fmaf(-2.0f, dotB, sz) + seb[cc + 1];
    if (dA < mind) { mind = dA; mini = v0 + cc; }       // strict <: low idx
    if (dB < mind) { mind = dB; mini = v0 + cc + 1; }
  }
  // monotone fp32->u32 encode (handles tiny negative d from rounding)
  unsigned int u = __float_as_uint(mind);
  u = (u & 0x80000000u) ? ~u : (u | 0x80000000u);
  unsigned long long key =
      ((unsigned long long)u << 32) | (unsigned int)mini;
  atomicMin(&keys[n], key);   // lexicographic (d, idx) min across chunks
}

// ------------- key -> idx (+ fp32 idx output) + fused loss ---------------
__global__ __launch_bounds__(256) void vq_reduce_loss_kernel(
    const unsigned long long* __restrict__ keys,
    const float* __restrict__ zpack, const float* __restrict__ embed,
    int* __restrict__ idx_list, float* __restrict__ idx_out_f,
    float* __restrict__ loss_slot)
{
  int n = blockIdx.x * 256 + threadIdx.x;
  int bi = (int)(unsigned int)(keys[n] & 0xffffffffull);
  idx_list[n] = bi;
  idx_out_f[n] = (float)bi;

  const float* zp = zpack + (size_t)n * 32;
  const float* ep = embed + (size_t)bi * 32;
  float s = 0.f;
#pragma unroll
  for (int c = 0; c < 32; ++c) {
    float d = ep[c] - zp[c];
    s = fmaf(d, d, s);
  }
#pragma unroll
  for (int off = 32; off > 0; off >>= 1) s += __shfl_down(s, off, 64);
  if ((threadIdx.x & 63) == 0) atomicAdd(loss_slot, s);
}

// ------- bicubic upsample + f_hat/f_rest update + NEXT-scale downsample ----
// block = one (b,c) 16x16 plane: blockIdx.x = b*32+c, tid = o*16+p
__global__ __launch_bounds__(256) void up_update_kernel(
    const float* __restrict__ embed, const int* __restrict__ idx_list,
    const float* __restrict__ tbl, float* __restrict__ f_hat,
    float* __restrict__ f_rest, int pn,
    float* __restrict__ zpack_next, unsigned long long* __restrict__ keys,
    int pn_next, int n_next)
{
  const int tid = threadIdx.x;
  const int t = blockIdx.x * 256 + tid;
  const int p = tid & 15, o = tid >> 4;
  const int c = blockIdx.x & 31, b = blockIdx.x >> 5;
  const float* Wo = tbl + o * 8;
  const float* Wp = tbl + p * 8;
  float acc = 0.f;
  for (int w = 0; w < pn; ++w) {
    float inner = 0.f;                 // ref: h-einsum first, then w
    for (int h = 0; h < pn; ++h) {
      int idx = idx_list[(b * pn + h) * pn + w];   // block-uniform gather
      inner = fmaf(Wo[h], embed[(size_t)idx * 32 + c], inner);
    }
    acc = fmaf(Wp[w], inner, acc);
  }
  float nr = f_rest[t] - acc;
  f_hat[t] += acc;
  f_rest[t] = nr;

  // downsample updated plane for the next scale (ref's exact i,j order)
  __shared__ float sm[256];
  sm[tid] = nr;
  __syncthreads();
  const int pnn2 = pn_next * pn_next;
  if (tid < pnn2) {
    int ph = tid / pn_next, pw = tid - ph * pn_next;
    int k = 16 / pn_next;
    float s = 0.f;
    for (int i = 0; i < k; ++i)
      for (int j = 0; j < k; ++j)
        s += sm[(ph * k + i) * 16 + (pw * k + j)];
    int n = b * pnn2 + ph * pn_next + pw;
    zpack_next[(size_t)n * 32 + c] = s * (1.0f / (k * k));  // 1/k^2 exact
  }
  if (t < n_next) keys[t] = ~0ull;     // reset argmin keys for next scale
}

// -------- last scale (pn=16): f_hat += embed[idx]; fold loss-final --------
__global__ __launch_bounds__(256) void final_add_kernel(
    const float* __restrict__ embed, const int* __restrict__ idx_list,
    float* __restrict__ f_hat, const float* __restrict__ losses,
    float* __restrict__ out_loss)
{
  int t = blockIdx.x * 256 + threadIdx.x;
  int s = t & 255;                  // o*16+p == spatial index at pn=16
  int c = (t >> 8) & 31;
  int b = t >> 13;
  int n = b * 256 + s;
  f_hat[t] += embed[(size_t)idx_list[n] * 32 + c];
  if (t == 0) {
    const float numel[5] = {8192.f, 32768.f, 131072.f, 524288.f, 2097152.f};
    float v = 0.f;
    for (int i = 0; i < 5; ++i) {
      float m = losses[i] / numel[i];
      v = v + (0.25f * m + m);       // beta*mean + mean
    }
    out_loss[0] = v / 5.f;
  }
}

// =========================== host launcher ===========================
extern "C" void kernel_launch(void* const* d_in, const int* in_sizes, int n_in,
                              void* d_out, int out_size, void* d_ws, size_t ws_size,
                              hipStream_t stream)
{
  const float* z     = (const float*)d_in[0];
  const float* embed = (const float*)d_in[1];
  float* out = (float*)d_out;
  float* ws  = (float*)d_ws;

  // ws layout (floats), total 4395528 floats ~= 17.6 MB
  float* f_rest = ws;                                   // 2097152
  float* zpack  = ws + 2097152;                         // 2097152
  float* se     = ws + 4194304;                         // 4096
  unsigned long long* keys = (unsigned long long*)(ws + 4198400); // 65536 u64
  int*   idx_list = (int*)(ws + 4329472);               // 65536
  float* losses   = ws + 4395008;                       // 8
  float* tables   = ws + 4395016;                       // 512

  setup_kernel<<<NTOT / 256, 256, 0, stream>>>(z, embed, f_rest, out, zpack,
                                               se, tables, losses, keys);

  const int PN[5]   = {1, 2, 4, 8, 16};
  const int BLKx[5] = {64, 64, 64, 256, 256};
  const int NV[5]   = {64, 64, 32, 32, 8};   // codebook chunks per scale
  int idx_off = NTOT;
  for (int i = 0; i < 5; ++i) {
    int pn = PN[i];
    int N  = B_ * pn * pn;
    int vchunk = V_ / NV[i];
    dim3 gA(N / BLKx[i], NV[i]);
    vq_point_kernel<<<gA, BLKx[i], 0, stream>>>(zpack, se, embed, keys, vchunk);
    vq_reduce_loss_kernel<<<N / 256, 256, 0, stream>>>(
        keys, zpack, embed, idx_list, out + idx_off, losses + i);
    if (i < 4)
      up_update_kernel<<<NTOT / 256, 256, 0, stream>>>(
          embed, idx_list, tables + i * 128, out, f_rest, pn,
          zpack, keys, PN[i + 1], B_ * PN[i + 1] * PN[i + 1]);
    else
      final_add_kernel<<<NTOT / 256, 256, 0, stream>>>(
          embed, idx_list, out, losses, out + 2184448);
    idx_off += N;
  }
}